// Round 7
// baseline (385.237 us; speedup 1.0000x reference)
//
#include <hip/hip_runtime.h>
#include <stdint.h>

// GAT 3-layer + linear head, MI355X (gfx950).
// I/O is FP32 (per reference). Internals: bf16 MFMA for h and att@h
// (softmax-averaging damps bf16 rounding); logits and final linear in fp32.
// R7: k_attn restructured barrier-free — j split across waves, MFMA B-operand
// loaded DIRECTLY global->VGPR (no LDS staging, no K-loop __syncthreads, so
// no vmcnt(0) barrier drain; compiler emits fine-grained vmcnt waits).

typedef unsigned short u16;
typedef __bf16 bf16x8 __attribute__((ext_vector_type(8)));
typedef float f32x4 __attribute__((ext_vector_type(4)));
typedef u16 u16x8 __attribute__((ext_vector_type(8)));

#define LOG2E 1.44269504088896340736f

__device__ __forceinline__ float b2f(u16 u) {
    union { unsigned int i; float f; } v; v.i = ((unsigned int)u) << 16; return v.f;
}
__device__ __forceinline__ u16 f2b(float f) {   // RNE round to bf16
    union { float f; unsigned int i; } v; v.f = f;
    unsigned int i = v.i;
    return (u16)((i + 0x7fffu + ((i >> 16) & 1u)) >> 16);
}
__device__ __forceinline__ float fast_exp2(float x) {
#if __has_builtin(__builtin_amdgcn_exp2f)
    return __builtin_amdgcn_exp2f(x);
#else
    return exp2f(x);
#endif
}

union ABfrag { bf16x8 v; u16x8 u; };

// ---------------- k_mask: adjacency bitmask, adjm[row][64] uint32 (bit j of row)
__global__ void __launch_bounds__(256) k_mask(const float* __restrict__ adj,
                                              uint32_t* __restrict__ adjm) {
    const int w = threadIdx.x >> 6, lane = threadIdx.x & 63;
    const int row = blockIdx.x * 4 + w;
    const float* ar = adj + (size_t)row * 2048;
    uint32_t* mr = adjm + (size_t)row * 64;
    for (int j0 = 0; j0 < 2048; j0 += 64) {
        unsigned long long m = __ballot(ar[j0 + lane] > 0.f);
        if (lane == 0) {
            mr[(j0 >> 5)] = (uint32_t)m;
            mr[(j0 >> 5) + 1] = (uint32_t)(m >> 32);
        }
    }
}

// ---------------- prep: bf16-transpose W's, u = (W @ a)*log2e (fp32)
__global__ void k_prep(const float* __restrict__ W1, const float* __restrict__ W2,
                       const float* __restrict__ W3,
                       const float* __restrict__ a1s, const float* __restrict__ a1d,
                       const float* __restrict__ a2s, const float* __restrict__ a2d,
                       const float* __restrict__ a3s, const float* __restrict__ a3d,
                       u16* __restrict__ Wt1, u16* __restrict__ Wt2, u16* __restrict__ Wt3,
                       float* __restrict__ u1s, float* __restrict__ u1d,
                       float* __restrict__ u2s, float* __restrict__ u2d,
                       float* __restrict__ u3s, float* __restrict__ u3d) {
    if (blockIdx.x == 160) {                 // u-vectors: fp32 matvecs, trivial size
        int f = threadIdx.x;
        if (f < 128) {
            float s1 = 0.f, d1 = 0.f, s2 = 0.f, d2 = 0.f, s3 = 0.f, d3 = 0.f;
            for (int o = 0; o < 128; ++o) { float w = W1[f * 128 + o]; s1 += w * a1s[o]; d1 += w * a1d[o]; }
            for (int o = 0; o < 128; ++o) { float w = W2[f * 128 + o]; s2 += w * a2s[o]; d2 += w * a2d[o]; }
            for (int o = 0; o <  64; ++o) { float w = W3[f *  64 + o]; s3 += w * a3s[o]; d3 += w * a3d[o]; }
            u1s[f] = s1 * LOG2E; u1d[f] = d1 * LOG2E;
            u2s[f] = s2 * LOG2E; u2d[f] = d2 * LOG2E;
            u3s[f] = s3 * LOG2E; u3d[f] = d3 * LOG2E;
        }
        return;
    }
    int idx = blockIdx.x * 256 + threadIdx.x;
    if (idx < 16384) {                       // W1: [128,128] -> Wt1[o][f] bf16
        int f = idx >> 7, o = idx & 127;
        Wt1[o * 128 + f] = f2b(W1[idx]);
    } else if (idx < 32768) {                // W2
        int j = idx - 16384; int f = j >> 7, o = j & 127;
        Wt2[o * 128 + f] = f2b(W2[j]);
    } else if (idx < 40960) {                // W3: [128,64] -> Wt3[o][f]
        int j = idx - 32768; int f = j >> 6, o = j & 63;
        Wt3[o * 128 + f] = f2b(W3[j]);
    }
}

// ---------------- k_h: h = act @ W (bf16 MFMA) -> h^T bf16; es/ed = act . u (fp32)
// grid (8, 32) = (b, nblk), block 256 (4 waves x 16 rows). K = 128 always.
template <int F, bool XF32>
__global__ void __launch_bounds__(256) k_h(const void* __restrict__ xv,
                                           const u16* __restrict__ Wt,
                                           const float* __restrict__ us,
                                           const float* __restrict__ ud,
                                           u16* __restrict__ h_t,
                                           float* __restrict__ es2,
                                           float* __restrict__ ed2) {
    constexpr int NT = F / 16;
    constexpr int TNP = 72;                  // padded n-stride (144B = 9x16B)
    __shared__ __align__(16) u16 hl[F * TNP];

    const int b = blockIdx.x;
    const int nblk = blockIdx.y;
    const int tid = threadIdx.x;
    const int w = tid >> 6, lane = tid & 63;
    const int quad = lane >> 4, l15 = lane & 15;
    const int n0w = nblk * 64 + w * 16;
    const int i_a = n0w + l15;               // A-operand row (m = lane&15)

    ABfrag afr[4];
    float ps = 0.f, pd = 0.f;
    if (XF32) {
        const float* xr = (const float*)xv + ((size_t)(b * 2048 + i_a)) * 128;
#pragma unroll
        for (int kk = 0; kk < 4; ++kk) {
            const int o8 = kk * 32 + quad * 8;
            float4 x0 = *reinterpret_cast<const float4*>(xr + o8);
            float4 x1 = *reinterpret_cast<const float4*>(xr + o8 + 4);
            float4 s0 = *reinterpret_cast<const float4*>(us + o8);
            float4 s1 = *reinterpret_cast<const float4*>(us + o8 + 4);
            float4 d0 = *reinterpret_cast<const float4*>(ud + o8);
            float4 d1 = *reinterpret_cast<const float4*>(ud + o8 + 4);
            ps += x0.x * s0.x + x0.y * s0.y + x0.z * s0.z + x0.w * s0.w
                + x1.x * s1.x + x1.y * s1.y + x1.z * s1.z + x1.w * s1.w;
            pd += x0.x * d0.x + x0.y * d0.y + x0.z * d0.z + x0.w * d0.w
                + x1.x * d1.x + x1.y * d1.y + x1.z * d1.z + x1.w * d1.w;
            afr[kk].u[0] = f2b(x0.x); afr[kk].u[1] = f2b(x0.y);
            afr[kk].u[2] = f2b(x0.z); afr[kk].u[3] = f2b(x0.w);
            afr[kk].u[4] = f2b(x1.x); afr[kk].u[5] = f2b(x1.y);
            afr[kk].u[6] = f2b(x1.z); afr[kk].u[7] = f2b(x1.w);
        }
    } else {
        const u16* xr = (const u16*)xv + ((size_t)(b * 2048 + i_a)) * 128;
#pragma unroll
        for (int kk = 0; kk < 4; ++kk) {
            const int o8 = kk * 32 + quad * 8;
            u16x8 xa = *reinterpret_cast<const u16x8*>(xr + o8);
            afr[kk].u = xa;
            float4 s0 = *reinterpret_cast<const float4*>(us + o8);
            float4 s1 = *reinterpret_cast<const float4*>(us + o8 + 4);
            float4 d0 = *reinterpret_cast<const float4*>(ud + o8);
            float4 d1 = *reinterpret_cast<const float4*>(ud + o8 + 4);
            float xf[8];
#pragma unroll
            for (int j = 0; j < 8; ++j) xf[j] = b2f(xa[j]);
            ps += xf[0] * s0.x + xf[1] * s0.y + xf[2] * s0.z + xf[3] * s0.w
                + xf[4] * s1.x + xf[5] * s1.y + xf[6] * s1.z + xf[7] * s1.w;
            pd += xf[0] * d0.x + xf[1] * d0.y + xf[2] * d0.z + xf[3] * d0.w
                + xf[4] * d1.x + xf[5] * d1.y + xf[6] * d1.z + xf[7] * d1.w;
        }
    }
    // reduce logit partials across the 4 quads sharing l15 (full 128-dot)
    ps += __shfl_xor(ps, 16, 64); ps += __shfl_xor(ps, 32, 64);
    pd += __shfl_xor(pd, 16, 64); pd += __shfl_xor(pd, 32, 64);
    if (quad == 0) {
        es2[b * 2048 + i_a] = ps;            // already *log2e via u pre-scale
        ed2[b * 2048 + i_a] = pd;
    }

    f32x4 acc[NT];
#pragma unroll
    for (int nt = 0; nt < NT; ++nt) acc[nt] = (f32x4){0.f, 0.f, 0.f, 0.f};
#pragma unroll
    for (int kk = 0; kk < 4; ++kk) {
#pragma unroll
        for (int nt = 0; nt < NT; ++nt) {
            bf16x8 bfv = *reinterpret_cast<const bf16x8*>(
                Wt + (nt * 16 + l15) * 128 + kk * 32 + quad * 8);
            acc[nt] = __builtin_amdgcn_mfma_f32_16x16x32_bf16(afr[kk].v, bfv, acc[nt], 0, 0, 0);
        }
    }

    // stage transposed tile to LDS (D: col=l15 -> o, row=quad*4+r -> i), then
    // coalesced global write of h^T[b][o][n]
#pragma unroll
    for (int nt = 0; nt < NT; ++nt)
#pragma unroll
        for (int r = 0; r < 4; ++r)
            hl[(nt * 16 + l15) * TNP + w * 16 + quad * 4 + r] = f2b(acc[nt][r]);
    __syncthreads();
    if (tid < F * 2) {
        int o = tid >> 1, half = tid & 1;
        const u16* src = hl + o * TNP + half * 32;
        u16* dst = h_t + ((size_t)(b * F + o)) * 2048 + nblk * 64 + half * 32;
#pragma unroll
        for (int c = 0; c < 4; ++c)
            *reinterpret_cast<u16x8*>(dst + c * 8) =
                *reinterpret_cast<const u16x8*>(src + c * 8);
    }
}

// ---------------- k_attn: fused masked-softmax(P) @ H, barrier-free K-loop.
// grid (8, 64) = (b, iblk of 32 i-rows), block 256 = 4 waves.
// Wave w sweeps j in [w*512, (w+1)*512) for all 32 rows (2 MFMA i-groups);
// B-fragments load directly global->VGPR (register double-buffer, no LDS,
// no __syncthreads until the epilogue combine).
template <int F, bool OUT_F32>
__global__ void __launch_bounds__(256, 2) k_attn(const float* __restrict__ es2,
                                                 const float* __restrict__ ed2,
                                                 const uint32_t* __restrict__ adjm,
                                                 const u16* __restrict__ h_t,
                                                 void* __restrict__ outp) {
    constexpr int NT = F / 16;
    __shared__ float accL[4][32][F];          // per-wave partial acc (F=128: 64 KB)
    __shared__ float dL[4][32];

    const int b = blockIdx.x;
    const int iblk = blockIdx.y;
    const int tid = threadIdx.x;
    const int w = tid >> 6, lane = tid & 63;
    const int quad = lane >> 4, l15 = lane & 15;
    const int i0 = iblk * 32;

    const float* edb = ed2 + b * 2048;
    const u16* hb = h_t + (size_t)b * F * 2048 + (size_t)l15 * 2048;  // + nt*16*2048 later
    float esv0 = es2[b * 2048 + i0 + l15];
    float esv1 = es2[b * 2048 + i0 + 16 + l15];
    const uint32_t* mr0 = adjm + (size_t)(i0 + l15) * 64 + w * 16;
    const uint32_t* mr1 = adjm + (size_t)(i0 + 16 + l15) * 64 + w * 16;
    const int j0w = w * 512 + quad * 8;       // this lane's j base

    f32x4 acc[2][NT];
#pragma unroll
    for (int ig = 0; ig < 2; ++ig)
#pragma unroll
        for (int nt = 0; nt < NT; ++nt) acc[ig][nt] = (f32x4){0.f, 0.f, 0.f, 0.f};
    float dacc0 = 0.f, dacc1 = 0.f;

    ABfrag Br[2][NT];
    float4 e0r[2], e1r[2];
    uint32_t m0r[2], m1r[2];

    // prologue: step 0 loads into slot 0
#pragma unroll
    for (int nt = 0; nt < NT; ++nt)
        Br[0][nt].u = *reinterpret_cast<const u16x8*>(hb + (size_t)nt * 16 * 2048 + j0w);
    e0r[0] = *reinterpret_cast<const float4*>(edb + j0w);
    e1r[0] = *reinterpret_cast<const float4*>(edb + j0w + 4);
    m0r[0] = mr0[0]; m1r[0] = mr1[0];

#pragma unroll
    for (int s = 0; s < 16; ++s) {
        const int cur = s & 1, nxt = cur ^ 1;
        if (s < 15) {                          // issue next-step loads (in flight over MFMA)
            const int jn = j0w + (s + 1) * 32;
#pragma unroll
            for (int nt = 0; nt < NT; ++nt)
                Br[nxt][nt].u = *reinterpret_cast<const u16x8*>(hb + (size_t)nt * 16 * 2048 + jn);
            e0r[nxt] = *reinterpret_cast<const float4*>(edb + jn);
            e1r[nxt] = *reinterpret_cast<const float4*>(edb + jn + 4);
            m0r[nxt] = mr0[s + 1]; m1r[nxt] = mr1[s + 1];
        }
        // P fragments (A-operand layout) for both i-groups
        float ed[8] = {e0r[cur].x, e0r[cur].y, e0r[cur].z, e0r[cur].w,
                       e1r[cur].x, e1r[cur].y, e1r[cur].z, e1r[cur].w};
        ABfrag af0, af1;
#pragma unroll
        for (int jj = 0; jj < 8; ++jj) {
            float e = esv0 + ed[jj];
            float v = fmaxf(e, 0.2f * e);
            float wv = fast_exp2(v);
            wv = ((m0r[cur] >> (quad * 8 + jj)) & 1u) ? wv : 0.f;
            u16 wb = f2b(wv); af0.u[jj] = wb; dacc0 += b2f(wb);
            e = esv1 + ed[jj];
            v = fmaxf(e, 0.2f * e);
            wv = fast_exp2(v);
            wv = ((m1r[cur] >> (quad * 8 + jj)) & 1u) ? wv : 0.f;
            wb = f2b(wv); af1.u[jj] = wb; dacc1 += b2f(wb);
        }
#pragma unroll
        for (int nt = 0; nt < NT; ++nt) {
            acc[0][nt] = __builtin_amdgcn_mfma_f32_16x16x32_bf16(af0.v, Br[cur][nt].v, acc[0][nt], 0, 0, 0);
            acc[1][nt] = __builtin_amdgcn_mfma_f32_16x16x32_bf16(af1.v, Br[cur][nt].v, acc[1][nt], 0, 0, 0);
        }
    }

    // per-wave denom partial: reduce over quads (rows live at lane l15)
    dacc0 += __shfl_xor(dacc0, 16, 64); dacc0 += __shfl_xor(dacc0, 32, 64);
    dacc1 += __shfl_xor(dacc1, 16, 64); dacc1 += __shfl_xor(dacc1, 32, 64);
    if (quad == 0) { dL[w][l15] = dacc0; dL[w][16 + l15] = dacc1; }
    // export partial acc (D: row=quad*4+r, col=nt*16+l15)
#pragma unroll
    for (int ig = 0; ig < 2; ++ig)
#pragma unroll
        for (int nt = 0; nt < NT; ++nt)
#pragma unroll
            for (int r = 0; r < 4; ++r)
                accL[w][ig * 16 + quad * 4 + r][nt * 16 + l15] = acc[ig][nt][r];
    __syncthreads();

    // combine 4 wave-partials, normalize, activation, write
    const int i = tid >> 3;
    constexpr int nf = F / 8;
    const int f0 = (tid & 7) * nf;
    const float den = dL[0][i] + dL[1][i] + dL[2][i] + dL[3][i];
    const float dinv = 1.0f / fmaxf(den, 1e-30f);
    const size_t rowoff = ((size_t)(b * 2048 + i0 + i)) * F + f0;
    if (OUT_F32) {
        float* o3 = (float*)outp;
#pragma unroll
        for (int k = 0; k < nf; k += 4) {
            f32x4 s4 = *reinterpret_cast<const f32x4*>(&accL[0][i][f0 + k]);
            s4 += *reinterpret_cast<const f32x4*>(&accL[1][i][f0 + k]);
            s4 += *reinterpret_cast<const f32x4*>(&accL[2][i][f0 + k]);
            s4 += *reinterpret_cast<const f32x4*>(&accL[3][i][f0 + k]);
            f32x4 v;
#pragma unroll
            for (int c = 0; c < 4; ++c) v[c] = fmaxf(s4[c] * dinv, 0.f);
            *reinterpret_cast<f32x4*>((float*)o3 + rowoff + k) = v;
        }
    } else {
        u16* xo = (u16*)outp;
#pragma unroll
        for (int k = 0; k < nf; k += 8) {
            u16x8 pk;
#pragma unroll
            for (int c = 0; c < 8; ++c) {
                float sv = accL[0][i][f0 + k + c] + accL[1][i][f0 + k + c]
                         + accL[2][i][f0 + k + c] + accL[3][i][f0 + k + c];
                pk[c] = f2b(fmaxf(sv * dinv, 0.f));
            }
            *reinterpret_cast<u16x8*>(xo + rowoff + k) = pk;
        }
    }
}

// ---------------- final linear stage 1: [8,131072] fp32 @ [131072,128] fp32
// grid 512, block 256; block p owns k in [p*256,(p+1)*256); writes pbuf[p][b][o].
__global__ void __launch_bounds__(256) k_lin(const float* __restrict__ o3,
                                             const float* __restrict__ Wlin,
                                             float* __restrict__ pbuf) {
    __shared__ float xc[8][256];
    __shared__ float red[8][8][128];          // [kb][b][o] = 32 KB
    const int tid = threadIdx.x;
    const int k0 = blockIdx.x * 256;
    for (int idx = tid; idx < 2048; idx += 256) {
        int bb = idx >> 8, kk = idx & 255;
        xc[bb][kk] = o3[(size_t)bb * 131072 + k0 + kk];
    }
    __syncthreads();
    const int o4 = tid & 31;                  // float4 output group: o = 4*o4..4*o4+3
    const int kb = tid >> 5;                  // k band: 32 k each
    f32x4 acc[8];
#pragma unroll
    for (int bb = 0; bb < 8; ++bb) acc[bb] = (f32x4){0.f, 0.f, 0.f, 0.f};
    const float* wp = Wlin + (size_t)(k0 + kb * 32) * 128 + o4 * 4;
#pragma unroll 4
    for (int k = 0; k < 32; ++k) {
        f32x4 wv = *reinterpret_cast<const f32x4*>(wp + (size_t)k * 128);
#pragma unroll
        for (int bb = 0; bb < 8; ++bb) acc[bb] += wv * xc[bb][kb * 32 + k];
    }
#pragma unroll
    for (int bb = 0; bb < 8; ++bb)
        *reinterpret_cast<f32x4*>(&red[kb][bb][o4 * 4]) = acc[bb];
    __syncthreads();
    // fold 8 k-bands: thread handles 4 flat outputs
    const int f = tid * 4;
    const int bb = f >> 7, o = f & 127;
    f32x4 s = (f32x4){0.f, 0.f, 0.f, 0.f};
#pragma unroll
    for (int k2 = 0; k2 < 8; ++k2) s += *reinterpret_cast<const f32x4*>(&red[k2][bb][o]);
    *reinterpret_cast<f32x4*>(&pbuf[(size_t)blockIdx.x * 1024 + f]) = s;
}

// ---------------- stage 2: fold 512 partials + bias -> out
// grid 64 x 256: block owns 16 outputs; 16 threads/output sum strided partials.
__global__ void __launch_bounds__(256) k_bias(const float* __restrict__ pbuf,
                                              const float* __restrict__ blin,
                                              float* __restrict__ out) {
    __shared__ float red[256];
    const int tid = threadIdx.x;
    const int p16 = tid >> 4;                 // 16 p-groups
    const int fo = tid & 15;
    const int f0 = blockIdx.x * 16;
    float s = 0.f;
#pragma unroll 4
    for (int p = p16; p < 512; p += 16)
        s += pbuf[(size_t)p * 1024 + f0 + fo];
    red[tid] = s;
    __syncthreads();
    if (tid < 16) {
        float t = 0.f;
#pragma unroll
        for (int k = 0; k < 16; ++k) t += red[k * 16 + tid];
        out[f0 + tid] = t + blin[(f0 + tid) & 127];
    }
}

extern "C" void kernel_launch(void* const* d_in, const int* in_sizes, int n_in,
                              void* d_out, int out_size, void* d_ws, size_t ws_size,
                              hipStream_t stream) {
    (void)in_sizes; (void)n_in; (void)out_size;
    const float* x    = (const float*)d_in[0];
    const float* adj  = (const float*)d_in[1];
    const float* W1   = (const float*)d_in[2];
    const float* a1s  = (const float*)d_in[3];
    const float* a1d  = (const float*)d_in[4];
    const float* W2   = (const float*)d_in[5];
    const float* a2s  = (const float*)d_in[6];
    const float* a2d  = (const float*)d_in[7];
    const float* W3   = (const float*)d_in[8];
    const float* a3s  = (const float*)d_in[9];
    const float* a3d  = (const float*)d_in[10];
    const float* Wlin = (const float*)d_in[11];
    const float* blin = (const float*)d_in[12];

    // ---- workspace layout (adaptive; never early-return) ----
    char* ws = (char*)d_ws;
    u16*   h_t = (u16*)ws;                          // 4 MB  [8][F][2048] bf16
    size_t off = (size_t)4 << 20;
    float* es2 = (float*)(ws + off); off += 65536;
    float* ed2 = (float*)(ws + off); off += 65536;
    u16*   Wt1 = (u16*)(ws + off);   off += 32768;
    u16*   Wt2 = (u16*)(ws + off);   off += 32768;
    u16*   Wt3 = (u16*)(ws + off);   off += 16384;
    float* u1s = (float*)(ws + off); off += 512;
    float* u1d = (float*)(ws + off); off += 512;
    float* u2s = (float*)(ws + off); off += 512;
    float* u2d = (float*)(ws + off); off += 512;
    float* u3s = (float*)(ws + off); off += 512;
    float* u3d = (float*)(ws + off); off += 512;
    uint32_t* adjm = (uint32_t*)(ws + off); off += 524288;    // [2048][64] bitmask
    float* pbuf = (float*)(ws + off); off += (size_t)512 * 1024 * 4;  // 2 MB partials
    // activation ping (bf16 [8][2048][128] = 4MB) aliases layer-3 fp32 out
    // ([8][2048][64] fp32 = 4MB): disjoint live ranges. Fallback: alias the x
    // input (16MB fp32; dead after layer-1 k_h; restored by harness pre-launch).
    u16* actA;
    if (ws_size >= off + ((size_t)4 << 20)) {
        actA = (u16*)(ws + off);
    } else {
        actA = (u16*)d_in[0];
    }
    float* o3 = (float*)actA;

    dim3 gh(8, 32);
    dim3 ga(8, 64);
    k_mask<<<512, 256, 0, stream>>>(adj, adjm);
    k_prep<<<161, 256, 0, stream>>>(W1, W2, W3, a1s, a1d, a2s, a2d, a3s, a3d,
                                    Wt1, Wt2, Wt3, u1s, u1d, u2s, u2d, u3s, u3d);

    k_h<128, true ><<<gh, 256, 0, stream>>>((const void*)x, Wt1, u1s, u1d, h_t, es2, ed2);
    k_attn<128, false><<<ga, 256, 0, stream>>>(es2, ed2, adjm, h_t, (void*)actA);

    k_h<128, false><<<gh, 256, 0, stream>>>((const void*)actA, Wt2, u2s, u2d, h_t, es2, ed2);
    k_attn<128, false><<<ga, 256, 0, stream>>>(es2, ed2, adjm, h_t, (void*)actA);

    k_h<64, false><<<gh, 256, 0, stream>>>((const void*)actA, Wt3, u3s, u3d, h_t, es2, ed2);
    k_attn<64, true ><<<ga, 256, 0, stream>>>(es2, ed2, adjm, h_t, (void*)o3);

    k_lin<<<512, 256, 0, stream>>>(o3, Wlin, pbuf);
    k_bias<<<64, 256, 0, stream>>>(pbuf, blin, (float*)d_out);
}

// Round 8
// 295.472 us; speedup vs baseline: 1.3038x; 1.3038x over previous
//
#include <hip/hip_runtime.h>
#include <stdint.h>

// GAT 3-layer + linear head, MI355X (gfx950).
// I/O is FP32 (per reference). Internals: bf16 MFMA for h and att@h
// (softmax-averaging damps bf16 rounding); logits and final linear in fp32.
// R8: fix R7's scratch spill — double-buffer via TWO EXPLICIT register sets
// (no runtime-indexed private arrays -> no scratch), pad accL (+4) for banks.

typedef unsigned short u16;
typedef __bf16 bf16x8 __attribute__((ext_vector_type(8)));
typedef float f32x4 __attribute__((ext_vector_type(4)));
typedef u16 u16x8 __attribute__((ext_vector_type(8)));

#define LOG2E 1.44269504088896340736f

__device__ __forceinline__ float b2f(u16 u) {
    union { unsigned int i; float f; } v; v.i = ((unsigned int)u) << 16; return v.f;
}
__device__ __forceinline__ u16 f2b(float f) {   // RNE round to bf16
    union { float f; unsigned int i; } v; v.f = f;
    unsigned int i = v.i;
    return (u16)((i + 0x7fffu + ((i >> 16) & 1u)) >> 16);
}
__device__ __forceinline__ float fast_exp2(float x) {
#if __has_builtin(__builtin_amdgcn_exp2f)
    return __builtin_amdgcn_exp2f(x);
#else
    return exp2f(x);
#endif
}

union ABfrag { bf16x8 v; u16x8 u; };

// ---------------- k_mask: adjacency bitmask, adjm[row][64] uint32 (bit j of row)
__global__ void __launch_bounds__(256) k_mask(const float* __restrict__ adj,
                                              uint32_t* __restrict__ adjm) {
    const int w = threadIdx.x >> 6, lane = threadIdx.x & 63;
    const int row = blockIdx.x * 4 + w;
    const float* ar = adj + (size_t)row * 2048;
    uint32_t* mr = adjm + (size_t)row * 64;
    for (int j0 = 0; j0 < 2048; j0 += 64) {
        unsigned long long m = __ballot(ar[j0 + lane] > 0.f);
        if (lane == 0) {
            mr[(j0 >> 5)] = (uint32_t)m;
            mr[(j0 >> 5) + 1] = (uint32_t)(m >> 32);
        }
    }
}

// ---------------- prep: bf16-transpose W's, u = (W @ a)*log2e (fp32)
__global__ void k_prep(const float* __restrict__ W1, const float* __restrict__ W2,
                       const float* __restrict__ W3,
                       const float* __restrict__ a1s, const float* __restrict__ a1d,
                       const float* __restrict__ a2s, const float* __restrict__ a2d,
                       const float* __restrict__ a3s, const float* __restrict__ a3d,
                       u16* __restrict__ Wt1, u16* __restrict__ Wt2, u16* __restrict__ Wt3,
                       float* __restrict__ u1s, float* __restrict__ u1d,
                       float* __restrict__ u2s, float* __restrict__ u2d,
                       float* __restrict__ u3s, float* __restrict__ u3d) {
    if (blockIdx.x == 160) {                 // u-vectors: fp32 matvecs, trivial size
        int f = threadIdx.x;
        if (f < 128) {
            float s1 = 0.f, d1 = 0.f, s2 = 0.f, d2 = 0.f, s3 = 0.f, d3 = 0.f;
            for (int o = 0; o < 128; ++o) { float w = W1[f * 128 + o]; s1 += w * a1s[o]; d1 += w * a1d[o]; }
            for (int o = 0; o < 128; ++o) { float w = W2[f * 128 + o]; s2 += w * a2s[o]; d2 += w * a2d[o]; }
            for (int o = 0; o <  64; ++o) { float w = W3[f *  64 + o]; s3 += w * a3s[o]; d3 += w * a3d[o]; }
            u1s[f] = s1 * LOG2E; u1d[f] = d1 * LOG2E;
            u2s[f] = s2 * LOG2E; u2d[f] = d2 * LOG2E;
            u3s[f] = s3 * LOG2E; u3d[f] = d3 * LOG2E;
        }
        return;
    }
    int idx = blockIdx.x * 256 + threadIdx.x;
    if (idx < 16384) {                       // W1: [128,128] -> Wt1[o][f] bf16
        int f = idx >> 7, o = idx & 127;
        Wt1[o * 128 + f] = f2b(W1[idx]);
    } else if (idx < 32768) {                // W2
        int j = idx - 16384; int f = j >> 7, o = j & 127;
        Wt2[o * 128 + f] = f2b(W2[j]);
    } else if (idx < 40960) {                // W3: [128,64] -> Wt3[o][f]
        int j = idx - 32768; int f = j >> 6, o = j & 63;
        Wt3[o * 128 + f] = f2b(W3[j]);
    }
}

// ---------------- k_h: h = act @ W (bf16 MFMA) -> h^T bf16; es/ed = act . u (fp32)
// grid (8, 32) = (b, nblk), block 256 (4 waves x 16 rows). K = 128 always.
template <int F, bool XF32>
__global__ void __launch_bounds__(256) k_h(const void* __restrict__ xv,
                                           const u16* __restrict__ Wt,
                                           const float* __restrict__ us,
                                           const float* __restrict__ ud,
                                           u16* __restrict__ h_t,
                                           float* __restrict__ es2,
                                           float* __restrict__ ed2) {
    constexpr int NT = F / 16;
    constexpr int TNP = 72;                  // padded n-stride (144B = 9x16B)
    __shared__ __align__(16) u16 hl[F * TNP];

    const int b = blockIdx.x;
    const int nblk = blockIdx.y;
    const int tid = threadIdx.x;
    const int w = tid >> 6, lane = tid & 63;
    const int quad = lane >> 4, l15 = lane & 15;
    const int n0w = nblk * 64 + w * 16;
    const int i_a = n0w + l15;               // A-operand row (m = lane&15)

    ABfrag afr[4];
    float ps = 0.f, pd = 0.f;
    if (XF32) {
        const float* xr = (const float*)xv + ((size_t)(b * 2048 + i_a)) * 128;
#pragma unroll
        for (int kk = 0; kk < 4; ++kk) {
            const int o8 = kk * 32 + quad * 8;
            float4 x0 = *reinterpret_cast<const float4*>(xr + o8);
            float4 x1 = *reinterpret_cast<const float4*>(xr + o8 + 4);
            float4 s0 = *reinterpret_cast<const float4*>(us + o8);
            float4 s1 = *reinterpret_cast<const float4*>(us + o8 + 4);
            float4 d0 = *reinterpret_cast<const float4*>(ud + o8);
            float4 d1 = *reinterpret_cast<const float4*>(ud + o8 + 4);
            ps += x0.x * s0.x + x0.y * s0.y + x0.z * s0.z + x0.w * s0.w
                + x1.x * s1.x + x1.y * s1.y + x1.z * s1.z + x1.w * s1.w;
            pd += x0.x * d0.x + x0.y * d0.y + x0.z * d0.z + x0.w * d0.w
                + x1.x * d1.x + x1.y * d1.y + x1.z * d1.z + x1.w * d1.w;
            afr[kk].u[0] = f2b(x0.x); afr[kk].u[1] = f2b(x0.y);
            afr[kk].u[2] = f2b(x0.z); afr[kk].u[3] = f2b(x0.w);
            afr[kk].u[4] = f2b(x1.x); afr[kk].u[5] = f2b(x1.y);
            afr[kk].u[6] = f2b(x1.z); afr[kk].u[7] = f2b(x1.w);
        }
    } else {
        const u16* xr = (const u16*)xv + ((size_t)(b * 2048 + i_a)) * 128;
#pragma unroll
        for (int kk = 0; kk < 4; ++kk) {
            const int o8 = kk * 32 + quad * 8;
            u16x8 xa = *reinterpret_cast<const u16x8*>(xr + o8);
            afr[kk].u = xa;
            float4 s0 = *reinterpret_cast<const float4*>(us + o8);
            float4 s1 = *reinterpret_cast<const float4*>(us + o8 + 4);
            float4 d0 = *reinterpret_cast<const float4*>(ud + o8);
            float4 d1 = *reinterpret_cast<const float4*>(ud + o8 + 4);
            float xf[8];
#pragma unroll
            for (int j = 0; j < 8; ++j) xf[j] = b2f(xa[j]);
            ps += xf[0] * s0.x + xf[1] * s0.y + xf[2] * s0.z + xf[3] * s0.w
                + xf[4] * s1.x + xf[5] * s1.y + xf[6] * s1.z + xf[7] * s1.w;
            pd += xf[0] * d0.x + xf[1] * d0.y + xf[2] * d0.z + xf[3] * d0.w
                + xf[4] * d1.x + xf[5] * d1.y + xf[6] * d1.z + xf[7] * d1.w;
        }
    }
    // reduce logit partials across the 4 quads sharing l15 (full 128-dot)
    ps += __shfl_xor(ps, 16, 64); ps += __shfl_xor(ps, 32, 64);
    pd += __shfl_xor(pd, 16, 64); pd += __shfl_xor(pd, 32, 64);
    if (quad == 0) {
        es2[b * 2048 + i_a] = ps;            // already *log2e via u pre-scale
        ed2[b * 2048 + i_a] = pd;
    }

    f32x4 acc[NT];
#pragma unroll
    for (int nt = 0; nt < NT; ++nt) acc[nt] = (f32x4){0.f, 0.f, 0.f, 0.f};
#pragma unroll
    for (int kk = 0; kk < 4; ++kk) {
#pragma unroll
        for (int nt = 0; nt < NT; ++nt) {
            bf16x8 bfv = *reinterpret_cast<const bf16x8*>(
                Wt + (nt * 16 + l15) * 128 + kk * 32 + quad * 8);
            acc[nt] = __builtin_amdgcn_mfma_f32_16x16x32_bf16(afr[kk].v, bfv, acc[nt], 0, 0, 0);
        }
    }

    // stage transposed tile to LDS (D: col=l15 -> o, row=quad*4+r -> i), then
    // coalesced global write of h^T[b][o][n]
#pragma unroll
    for (int nt = 0; nt < NT; ++nt)
#pragma unroll
        for (int r = 0; r < 4; ++r)
            hl[(nt * 16 + l15) * TNP + w * 16 + quad * 4 + r] = f2b(acc[nt][r]);
    __syncthreads();
    if (tid < F * 2) {
        int o = tid >> 1, half = tid & 1;
        const u16* src = hl + o * TNP + half * 32;
        u16* dst = h_t + ((size_t)(b * F + o)) * 2048 + nblk * 64 + half * 32;
#pragma unroll
        for (int c = 0; c < 4; ++c)
            *reinterpret_cast<u16x8*>(dst + c * 8) =
                *reinterpret_cast<const u16x8*>(src + c * 8);
    }
}

// ---------------- k_attn: fused masked-softmax(P) @ H, barrier-free K-loop.
// grid (8, 64) = (b, iblk of 32 i-rows), block 256 = 4 waves.
// Wave w sweeps j in [w*512, (w+1)*512) for 32 rows (2 MFMA i-groups);
// B-fragments load directly global->VGPR. Double-buffer = TWO EXPLICIT
// register sets (A/B) so no runtime-indexed private arrays (no scratch).
template <int F, bool OUT_F32>
__global__ void __launch_bounds__(256, 2) k_attn(const float* __restrict__ es2,
                                                 const float* __restrict__ ed2,
                                                 const uint32_t* __restrict__ adjm,
                                                 const u16* __restrict__ h_t,
                                                 void* __restrict__ outp) {
    constexpr int NT = F / 16;
    constexpr int FP = F + 4;                 // padded col stride (quad-lanes 16 banks apart)
    __shared__ float accL[4][32][FP];
    __shared__ float dL[4][32];

    const int b = blockIdx.x;
    const int iblk = blockIdx.y;
    const int tid = threadIdx.x;
    const int w = tid >> 6, lane = tid & 63;
    const int quad = lane >> 4, l15 = lane & 15;
    const int i0 = iblk * 32;

    const float* edb = ed2 + b * 2048;
    const u16* hb = h_t + (size_t)b * F * 2048 + (size_t)l15 * 2048;
    const float esv0 = es2[b * 2048 + i0 + l15];
    const float esv1 = es2[b * 2048 + i0 + 16 + l15];
    const uint32_t* mr0 = adjm + (size_t)(i0 + l15) * 64 + w * 16;
    const uint32_t* mr1 = adjm + (size_t)(i0 + 16 + l15) * 64 + w * 16;
    const int j0w = w * 512 + quad * 8;       // this lane's j base

    f32x4 acc[2][NT];
#pragma unroll
    for (int ig = 0; ig < 2; ++ig)
#pragma unroll
        for (int nt = 0; nt < NT; ++nt) acc[ig][nt] = (f32x4){0.f, 0.f, 0.f, 0.f};
    float dacc0 = 0.f, dacc1 = 0.f;

    ABfrag BrA[NT], BrB[NT];
    float4 eA0, eA1, eB0, eB1;
    uint32_t mA0, mA1, mB0, mB1;

    // prologue: load step-0 into set A
#pragma unroll
    for (int nt = 0; nt < NT; ++nt)
        BrA[nt].u = *reinterpret_cast<const u16x8*>(hb + (size_t)nt * 16 * 2048 + j0w);
    eA0 = *reinterpret_cast<const float4*>(edb + j0w);
    eA1 = *reinterpret_cast<const float4*>(edb + j0w + 4);
    mA0 = mr0[0]; mA1 = mr1[0];

    for (int p = 0; p < 8; ++p) {             // step pair (2p, 2p+1)
        // load set B for step 2p+1 (flies over set-A compute)
        {
            const int jn = j0w + (2 * p + 1) * 32;
#pragma unroll
            for (int nt = 0; nt < NT; ++nt)
                BrB[nt].u = *reinterpret_cast<const u16x8*>(hb + (size_t)nt * 16 * 2048 + jn);
            eB0 = *reinterpret_cast<const float4*>(edb + jn);
            eB1 = *reinterpret_cast<const float4*>(edb + jn + 4);
            mB0 = mr0[2 * p + 1]; mB1 = mr1[2 * p + 1];
        }
        // compute + MFMA with set A
        {
            float ed[8] = {eA0.x, eA0.y, eA0.z, eA0.w, eA1.x, eA1.y, eA1.z, eA1.w};
            ABfrag af0, af1;
#pragma unroll
            for (int jj = 0; jj < 8; ++jj) {
                float e = esv0 + ed[jj];
                float v = fmaxf(e, 0.2f * e);
                float wv = fast_exp2(v);
                wv = ((mA0 >> (quad * 8 + jj)) & 1u) ? wv : 0.f;
                u16 wb = f2b(wv); af0.u[jj] = wb; dacc0 += b2f(wb);
                e = esv1 + ed[jj];
                v = fmaxf(e, 0.2f * e);
                wv = fast_exp2(v);
                wv = ((mA1 >> (quad * 8 + jj)) & 1u) ? wv : 0.f;
                wb = f2b(wv); af1.u[jj] = wb; dacc1 += b2f(wb);
            }
#pragma unroll
            for (int nt = 0; nt < NT; ++nt) {
                acc[0][nt] = __builtin_amdgcn_mfma_f32_16x16x32_bf16(af0.v, BrA[nt].v, acc[0][nt], 0, 0, 0);
                acc[1][nt] = __builtin_amdgcn_mfma_f32_16x16x32_bf16(af1.v, BrA[nt].v, acc[1][nt], 0, 0, 0);
            }
        }
        // load set A for step 2p+2 (flies over set-B compute)
        if (p < 7) {
            const int jn = j0w + (2 * p + 2) * 32;
#pragma unroll
            for (int nt = 0; nt < NT; ++nt)
                BrA[nt].u = *reinterpret_cast<const u16x8*>(hb + (size_t)nt * 16 * 2048 + jn);
            eA0 = *reinterpret_cast<const float4*>(edb + jn);
            eA1 = *reinterpret_cast<const float4*>(edb + jn + 4);
            mA0 = mr0[2 * p + 2]; mA1 = mr1[2 * p + 2];
        }
        // compute + MFMA with set B
        {
            float ed[8] = {eB0.x, eB0.y, eB0.z, eB0.w, eB1.x, eB1.y, eB1.z, eB1.w};
            ABfrag af0, af1;
#pragma unroll
            for (int jj = 0; jj < 8; ++jj) {
                float e = esv0 + ed[jj];
                float v = fmaxf(e, 0.2f * e);
                float wv = fast_exp2(v);
                wv = ((mB0 >> (quad * 8 + jj)) & 1u) ? wv : 0.f;
                u16 wb = f2b(wv); af0.u[jj] = wb; dacc0 += b2f(wb);
                e = esv1 + ed[jj];
                v = fmaxf(e, 0.2f * e);
                wv = fast_exp2(v);
                wv = ((mB1 >> (quad * 8 + jj)) & 1u) ? wv : 0.f;
                wb = f2b(wv); af1.u[jj] = wb; dacc1 += b2f(wb);
            }
#pragma unroll
            for (int nt = 0; nt < NT; ++nt) {
                acc[0][nt] = __builtin_amdgcn_mfma_f32_16x16x32_bf16(af0.v, BrB[nt].v, acc[0][nt], 0, 0, 0);
                acc[1][nt] = __builtin_amdgcn_mfma_f32_16x16x32_bf16(af1.v, BrB[nt].v, acc[1][nt], 0, 0, 0);
            }
        }
    }

    // per-wave denom partial: reduce over quads (rows live at lane l15)
    dacc0 += __shfl_xor(dacc0, 16, 64); dacc0 += __shfl_xor(dacc0, 32, 64);
    dacc1 += __shfl_xor(dacc1, 16, 64); dacc1 += __shfl_xor(dacc1, 32, 64);
    if (quad == 0) { dL[w][l15] = dacc0; dL[w][16 + l15] = dacc1; }
    // export partial acc (D: row=quad*4+r, col=nt*16+l15)
#pragma unroll
    for (int ig = 0; ig < 2; ++ig)
#pragma unroll
        for (int nt = 0; nt < NT; ++nt)
#pragma unroll
            for (int r = 0; r < 4; ++r)
                accL[w][ig * 16 + quad * 4 + r][nt * 16 + l15] = acc[ig][nt][r];
    __syncthreads();

    // combine 4 wave-partials, normalize, activation, write
    const int i = tid >> 3;
    constexpr int nf = F / 8;
    const int f0 = (tid & 7) * nf;
    const float den = dL[0][i] + dL[1][i] + dL[2][i] + dL[3][i];
    const float dinv = 1.0f / fmaxf(den, 1e-30f);
    const size_t rowoff = ((size_t)(b * 2048 + i0 + i)) * F + f0;
    if (OUT_F32) {
        float* o3 = (float*)outp;
#pragma unroll
        for (int k = 0; k < nf; k += 4) {
            f32x4 s4 = *reinterpret_cast<const f32x4*>(&accL[0][i][f0 + k]);
            s4 += *reinterpret_cast<const f32x4*>(&accL[1][i][f0 + k]);
            s4 += *reinterpret_cast<const f32x4*>(&accL[2][i][f0 + k]);
            s4 += *reinterpret_cast<const f32x4*>(&accL[3][i][f0 + k]);
            f32x4 v;
#pragma unroll
            for (int c = 0; c < 4; ++c) v[c] = fmaxf(s4[c] * dinv, 0.f);
            *reinterpret_cast<f32x4*>((float*)o3 + rowoff + k) = v;
        }
    } else {
        u16* xo = (u16*)outp;
#pragma unroll
        for (int k = 0; k < nf; k += 8) {
            u16x8 pk;
#pragma unroll
            for (int c = 0; c < 8; ++c) {
                float sv = accL[0][i][f0 + k + c] + accL[1][i][f0 + k + c]
                         + accL[2][i][f0 + k + c] + accL[3][i][f0 + k + c];
                pk[c] = f2b(fmaxf(sv * dinv, 0.f));
            }
            *reinterpret_cast<u16x8*>(xo + rowoff + k) = pk;
        }
    }
}

// ---------------- final linear stage 1: [8,131072] fp32 @ [131072,128] fp32
// grid 512, block 256; block p owns k in [p*256,(p+1)*256); writes pbuf[p][b][o].
__global__ void __launch_bounds__(256) k_lin(const float* __restrict__ o3,
                                             const float* __restrict__ Wlin,
                                             float* __restrict__ pbuf) {
    __shared__ float xc[8][256];
    __shared__ float red[8][8][128];          // [kb][b][o] = 32 KB
    const int tid = threadIdx.x;
    const int k0 = blockIdx.x * 256;
    for (int idx = tid; idx < 2048; idx += 256) {
        int bb = idx >> 8, kk = idx & 255;
        xc[bb][kk] = o3[(size_t)bb * 131072 + k0 + kk];
    }
    __syncthreads();
    const int o4 = tid & 31;                  // float4 output group: o = 4*o4..4*o4+3
    const int kb = tid >> 5;                  // k band: 32 k each
    f32x4 acc[8];
#pragma unroll
    for (int bb = 0; bb < 8; ++bb) acc[bb] = (f32x4){0.f, 0.f, 0.f, 0.f};
    const float* wp = Wlin + (size_t)(k0 + kb * 32) * 128 + o4 * 4;
#pragma unroll 4
    for (int k = 0; k < 32; ++k) {
        f32x4 wv = *reinterpret_cast<const f32x4*>(wp + (size_t)k * 128);
#pragma unroll
        for (int bb = 0; bb < 8; ++bb) acc[bb] += wv * xc[bb][kb * 32 + k];
    }
#pragma unroll
    for (int bb = 0; bb < 8; ++bb)
        *reinterpret_cast<f32x4*>(&red[kb][bb][o4 * 4]) = acc[bb];
    __syncthreads();
    // fold 8 k-bands: thread handles 4 flat outputs
    const int f = tid * 4;
    const int bb = f >> 7, o = f & 127;
    f32x4 s = (f32x4){0.f, 0.f, 0.f, 0.f};
#pragma unroll
    for (int k2 = 0; k2 < 8; ++k2) s += *reinterpret_cast<const f32x4*>(&red[k2][bb][o]);
    *reinterpret_cast<f32x4*>(&pbuf[(size_t)blockIdx.x * 1024 + f]) = s;
}

// ---------------- stage 2: fold 512 partials + bias -> out
// grid 64 x 256: block owns 16 outputs; 16 threads/output sum strided partials.
__global__ void __launch_bounds__(256) k_bias(const float* __restrict__ pbuf,
                                              const float* __restrict__ blin,
                                              float* __restrict__ out) {
    __shared__ float red[256];
    const int tid = threadIdx.x;
    const int p16 = tid >> 4;                 // 16 p-groups
    const int fo = tid & 15;
    const int f0 = blockIdx.x * 16;
    float s = 0.f;
#pragma unroll 4
    for (int p = p16; p < 512; p += 16)
        s += pbuf[(size_t)p * 1024 + f0 + fo];
    red[tid] = s;
    __syncthreads();
    if (tid < 16) {
        float t = 0.f;
#pragma unroll
        for (int k = 0; k < 16; ++k) t += red[k * 16 + tid];
        out[f0 + tid] = t + blin[(f0 + tid) & 127];
    }
}

extern "C" void kernel_launch(void* const* d_in, const int* in_sizes, int n_in,
                              void* d_out, int out_size, void* d_ws, size_t ws_size,
                              hipStream_t stream) {
    (void)in_sizes; (void)n_in; (void)out_size;
    const float* x    = (const float*)d_in[0];
    const float* adj  = (const float*)d_in[1];
    const float* W1   = (const float*)d_in[2];
    const float* a1s  = (const float*)d_in[3];
    const float* a1d  = (const float*)d_in[4];
    const float* W2   = (const float*)d_in[5];
    const float* a2s  = (const float*)d_in[6];
    const float* a2d  = (const float*)d_in[7];
    const float* W3   = (const float*)d_in[8];
    const float* a3s  = (const float*)d_in[9];
    const float* a3d  = (const float*)d_in[10];
    const float* Wlin = (const float*)d_in[11];
    const float* blin = (const float*)d_in[12];

    // ---- workspace layout (adaptive; never early-return) ----
    char* ws = (char*)d_ws;
    u16*   h_t = (u16*)ws;                          // 4 MB  [8][F][2048] bf16
    size_t off = (size_t)4 << 20;
    float* es2 = (float*)(ws + off); off += 65536;
    float* ed2 = (float*)(ws + off); off += 65536;
    u16*   Wt1 = (u16*)(ws + off);   off += 32768;
    u16*   Wt2 = (u16*)(ws + off);   off += 32768;
    u16*   Wt3 = (u16*)(ws + off);   off += 16384;
    float* u1s = (float*)(ws + off); off += 512;
    float* u1d = (float*)(ws + off); off += 512;
    float* u2s = (float*)(ws + off); off += 512;
    float* u2d = (float*)(ws + off); off += 512;
    float* u3s = (float*)(ws + off); off += 512;
    float* u3d = (float*)(ws + off); off += 512;
    uint32_t* adjm = (uint32_t*)(ws + off); off += 524288;    // [2048][64] bitmask
    float* pbuf = (float*)(ws + off); off += (size_t)512 * 1024 * 4;  // 2 MB partials
    // activation ping (bf16 [8][2048][128] = 4MB) aliases layer-3 fp32 out
    // ([8][2048][64] fp32 = 4MB): disjoint live ranges. Fallback: alias the x
    // input (16MB fp32; dead after layer-1 k_h; restored by harness pre-launch).
    u16* actA;
    if (ws_size >= off + ((size_t)4 << 20)) {
        actA = (u16*)(ws + off);
    } else {
        actA = (u16*)d_in[0];
    }
    float* o3 = (float*)actA;

    dim3 gh(8, 32);
    dim3 ga(8, 64);
    k_mask<<<512, 256, 0, stream>>>(adj, adjm);
    k_prep<<<161, 256, 0, stream>>>(W1, W2, W3, a1s, a1d, a2s, a2d, a3s, a3d,
                                    Wt1, Wt2, Wt3, u1s, u1d, u2s, u2d, u3s, u3d);

    k_h<128, true ><<<gh, 256, 0, stream>>>((const void*)x, Wt1, u1s, u1d, h_t, es2, ed2);
    k_attn<128, false><<<ga, 256, 0, stream>>>(es2, ed2, adjm, h_t, (void*)actA);

    k_h<128, false><<<gh, 256, 0, stream>>>((const void*)actA, Wt2, u2s, u2d, h_t, es2, ed2);
    k_attn<128, false><<<ga, 256, 0, stream>>>(es2, ed2, adjm, h_t, (void*)actA);

    k_h<64, false><<<gh, 256, 0, stream>>>((const void*)actA, Wt3, u3s, u3d, h_t, es2, ed2);
    k_attn<64, true ><<<ga, 256, 0, stream>>>(es2, ed2, adjm, h_t, (void*)o3);

    k_lin<<<512, 256, 0, stream>>>(o3, Wlin, pbuf);
    k_bias<<<64, 256, 0, stream>>>(pbuf, blin, (float*)d_out);
}